// Round 4
// baseline (622.266 us; speedup 1.0000x reference)
//
#include <hip/hip_runtime.h>
#include <math.h>

typedef __attribute__((ext_vector_type(8))) short bf16x8;
typedef __attribute__((ext_vector_type(4))) short bf16x4_t;
typedef __attribute__((ext_vector_type(4))) float f32x4;
typedef __attribute__((ext_vector_type(4))) unsigned int u32x4;

static __device__ __forceinline__ float4 ld4(const float* p) {
    return *reinterpret_cast<const float4*>(p);
}
static __device__ __forceinline__ unsigned short f2bf(float f) {
    unsigned int u = __float_as_uint(f);
    u += 0x7fffu + ((u >> 16) & 1u);
    return (unsigned short)(u >> 16);
}

// ---------------------------------------------------------------------------
// LayerNorm: one wave per row of 512, bf16 output.
// mode=1: in_row = r + 1 + r/3136 (patch rows of (2,3137,512)).
// ---------------------------------------------------------------------------
__global__ __launch_bounds__(64) void ln_kernel(
    const float* __restrict__ in, const float* __restrict__ g,
    const float* __restrict__ bta, unsigned short* __restrict__ out, int mode)
{
    int r = blockIdx.x;
    int lane = threadIdx.x;
    int in_r = mode ? (r + 1 + r / 3136) : r;
    const float* xp = in + (size_t)in_r * 512 + lane * 8;
    float4 v0 = ld4(xp), v1 = ld4(xp + 4);
    float s  = v0.x + v0.y + v0.z + v0.w + v1.x + v1.y + v1.z + v1.w;
    float sq = v0.x*v0.x + v0.y*v0.y + v0.z*v0.z + v0.w*v0.w
             + v1.x*v1.x + v1.y*v1.y + v1.z*v1.z + v1.w*v1.w;
    #pragma unroll
    for (int off = 32; off; off >>= 1) {
        s  += __shfl_xor(s, off);
        sq += __shfl_xor(sq, off);
    }
    float mean = s * (1.f / 512.f);
    float var  = fmaxf(sq * (1.f / 512.f) - mean * mean, 0.f);
    float rstd = rsqrtf(var + 1e-5f);
    float4 g0 = ld4(g + lane * 8),   g1 = ld4(g + lane * 8 + 4);
    float4 b0 = ld4(bta + lane * 8), b1 = ld4(bta + lane * 8 + 4);
    float o0 = (v0.x - mean) * rstd * g0.x + b0.x;
    float o1 = (v0.y - mean) * rstd * g0.y + b0.y;
    float o2 = (v0.z - mean) * rstd * g0.z + b0.z;
    float o3 = (v0.w - mean) * rstd * g0.w + b0.w;
    float o4 = (v1.x - mean) * rstd * g1.x + b1.x;
    float o5 = (v1.y - mean) * rstd * g1.y + b1.y;
    float o6 = (v1.z - mean) * rstd * g1.z + b1.z;
    float o7 = (v1.w - mean) * rstd * g1.w + b1.w;
    u32x4 pk;
    pk[0] = (unsigned int)f2bf(o0) | ((unsigned int)f2bf(o1) << 16);
    pk[1] = (unsigned int)f2bf(o2) | ((unsigned int)f2bf(o3) << 16);
    pk[2] = (unsigned int)f2bf(o4) | ((unsigned int)f2bf(o5) << 16);
    pk[3] = (unsigned int)f2bf(o6) | ((unsigned int)f2bf(o7) << 16);
    *(u32x4*)(out + (size_t)r * 512 + lane * 8) = pk;
}

// ---------------------------------------------------------------------------
// Weight transpose + fp32->bf16: W[K][N] -> WT[N][K] bf16.
// ---------------------------------------------------------------------------
__global__ __launch_bounds__(256) void transpose_bf16_kernel(
    const float* __restrict__ W, unsigned short* __restrict__ WT, int K, int N)
{
    __shared__ unsigned short tile[32][34];
    int tx = threadIdx.x, ty = threadIdx.y;
    int bx = blockIdx.x * 32, by = blockIdx.y * 32;
    #pragma unroll
    for (int r = 0; r < 32; r += 8)
        tile[ty + r][tx] = f2bf(W[(size_t)(by + ty + r) * N + bx + tx]);
    __syncthreads();
    #pragma unroll
    for (int r = 0; r < 32; r += 8)
        WT[(size_t)(bx + ty + r) * K + by + tx] = tile[tx][ty + r];
}

// ---------------------------------------------------------------------------
// MFMA bf16 GEMM: out[maprow(m)] (+)= A[m,:] @ WT[n,:] + bias (+gelu)(+resid)
// A: MxK bf16, WT: (>=N)xK bf16. BM=BN=128, BK=32, 4 waves, 4x4 16x16x32 frags.
// biasrow: bias indexed by row (m) instead of col. vtNs!=0: "vT mode" output
// layout [batch][512 rows][vtNsP tokens], batch = col / vtNs via magic mul.
// ---------------------------------------------------------------------------
template<int OUT_BF16>
__global__ __launch_bounds__(256) void mfma_gemm(
    const unsigned short* __restrict__ A, const unsigned short* __restrict__ WT,
    const float* __restrict__ bias, const float* __restrict__ resid,
    void* __restrict__ outp, int M, int N, int K,
    int rowmap, int act, int biasrow,
    int vtNs, unsigned int vtMagic, int vtNsP)
{
    __shared__ __align__(16) unsigned short As[128][40];
    __shared__ __align__(16) unsigned short Bs[128][40];

    int tid = threadIdx.x;
    int m0 = blockIdx.x * 128, n0 = blockIdx.y * 128;
    int w = tid >> 6, l = tid & 63;
    int wm = (w >> 1) * 64, wn = (w & 1) * 64;
    int lr = l & 15, lg = l >> 4;

    f32x4 zero = {0.f, 0.f, 0.f, 0.f};
    f32x4 acc[4][4];
    #pragma unroll
    for (int i = 0; i < 4; ++i)
        #pragma unroll
        for (int j = 0; j < 4; ++j) acc[i][j] = zero;

    for (int k0 = 0; k0 < K; k0 += 32) {
        #pragma unroll
        for (int p = 0; p < 2; ++p) {
            int m = p * 64 + (tid >> 2);
            int k8 = (tid & 3) * 8;
            int row = m0 + m;
            u32x4 v = {0u, 0u, 0u, 0u};
            if (row < M) v = *(const u32x4*)(A + (size_t)row * K + k0 + k8);
            *(u32x4*)&As[m][k8] = v;
        }
        #pragma unroll
        for (int p = 0; p < 2; ++p) {
            int n = p * 64 + (tid >> 2);
            int k8 = (tid & 3) * 8;
            int nrow = n0 + n; if (nrow >= N) nrow = N - 1;
            u32x4 v = *(const u32x4*)(WT + (size_t)nrow * K + k0 + k8);
            *(u32x4*)&Bs[n][k8] = v;
        }
        __syncthreads();

        bf16x8 af[4], bfr[4];
        #pragma unroll
        for (int i = 0; i < 4; ++i)
            af[i] = *(const bf16x8*)&As[wm + i * 16 + lr][lg * 8];
        #pragma unroll
        for (int j = 0; j < 4; ++j)
            bfr[j] = *(const bf16x8*)&Bs[wn + j * 16 + lr][lg * 8];
        #pragma unroll
        for (int i = 0; i < 4; ++i)
            #pragma unroll
            for (int j = 0; j < 4; ++j)
                acc[i][j] = __builtin_amdgcn_mfma_f32_16x16x32_bf16(
                    af[i], bfr[j], acc[i][j], 0, 0, 0);
        __syncthreads();
    }

    // D layout: col = lane&15, row = (lane>>4)*4 + reg.
    #pragma unroll
    for (int i = 0; i < 4; ++i) {
        #pragma unroll
        for (int r = 0; r < 4; ++r) {
            int row = m0 + wm + i * 16 + lg * 4 + r;
            if (row >= M) continue;
            int orow = rowmap ? (row + 1 + row / 3136) : row;
            #pragma unroll
            for (int j = 0; j < 4; ++j) {
                int col = n0 + wn + j * 16 + lr;
                if (col >= N) continue;
                float v = acc[i][j][r] + (biasrow ? bias[row] : bias[col]);
                if (act) v = 0.5f * v * (1.f + erff(v * 0.70710678118654752f));
                if (resid) v += resid[(size_t)orow * N + col];
                if (vtNs) {
                    unsigned int bb = (unsigned int)(((unsigned long long)(unsigned int)col * vtMagic) >> 32);
                    int nn = col - (int)bb * vtNs;
                    ((unsigned short*)outp)[((size_t)bb * 512 + row) * vtNsP + nn] = f2bf(v);
                } else if (OUT_BF16) {
                    ((unsigned short*)outp)[(size_t)orow * N + col] = f2bf(v);
                } else {
                    ((float*)outp)[(size_t)orow * N + col] = v;
                }
            }
        }
    }
}

// ---------------------------------------------------------------------------
// MFMA flash attention, bf16, no P round-trip, V^T pre-transposed in global.
// qk: [Mtot][1024] rows = [q(512)|k(512)]; vT: [batch][512][NsP].
// Block = 4 waves x 16 q-rows. S^T = mfma(K, Q): lane -> q=lane&15,
// key_local = 16f + 4g + reg. P packed per-lane (key slot sigma:
// key(g,i) = 16*(i>>2) + 4g + (i&3)); V A-frag gathered with same sigma
// = two conflict-free ds_read_b64 from VsT[64][36] (stride-36 pad).
// ---------------------------------------------------------------------------
__global__ __launch_bounds__(256) void attn_mfma(
    const unsigned short* __restrict__ qk, const unsigned short* __restrict__ vT,
    unsigned short* __restrict__ o, int Ns, int NsP)
{
    __shared__ __align__(16) unsigned short Ks[32 * 64];
    __shared__ __align__(16) unsigned short VsT[64 * 36];

    int tid = threadIdx.x;
    int h = blockIdx.y, b = blockIdx.z;
    int mb = b * Ns;
    int l = tid & 63, w = tid >> 6;
    int g = l >> 4, c16 = l & 15;

    int qrow = blockIdx.x * 64 + w * 16 + c16;
    int qr = (qrow < Ns ? qrow : Ns - 1) + mb;
    const unsigned short* qp = qk + (size_t)qr * 1024 + h * 64;
    bf16x8 bQ0 = *(const bf16x8*)(qp + g * 8);
    bf16x8 bQ1 = *(const bf16x8*)(qp + 32 + g * 8);

    f32x4 zero = {0.f, 0.f, 0.f, 0.f};
    f32x4 Oacc[4] = {zero, zero, zero, zero};
    float mrun = -1e30f, lrun = 0.f;

    // K staging: thread -> key row sk, 16B chunk sch, xor-swizzled dest.
    int sk = tid >> 3, sch = tid & 7;
    int kdst = sk * 64 + ((sch ^ (sk & 7) ^ (sk >> 3)) * 8);
    // V staging: thread -> dim sd, key chunk skc (8 keys).
    int sd = tid >> 2, skc = tid & 3;
    const unsigned short* vrow = vT + ((size_t)b * 512 + h * 64 + sd) * NsP;
    int vdst = sd * 36 + skc * 8;

    // Hoisted K-frag LDS offsets.
    int swz0 = (c16 & 7) ^ (c16 >> 3);
    int swz1 = (c16 & 7) ^ ((16 + c16) >> 3);
    int ka00 = c16 * 64 + ((g ^ swz0) * 8);
    int ka01 = c16 * 64 + (((4 + g) ^ swz0) * 8);
    int ka10 = (16 + c16) * 64 + ((g ^ swz1) * 8);
    int ka11 = (16 + c16) * 64 + (((4 + g) ^ swz1) * 8);

    const float L2E = 1.4426950408889634f;
    int nt = (Ns + 31) >> 5;
    for (int kt = 0; kt < nt; ++kt) {
        int kr = kt * 32 + sk; if (kr >= Ns) kr = Ns - 1;
        u32x4 kv = *(const u32x4*)(qk + (size_t)(mb + kr) * 1024 + 512 + h * 64 + sch * 8);
        u32x4 vv = *(const u32x4*)(vrow + kt * 32 + skc * 8);
        __syncthreads();                    // prev tile fully consumed
        *(u32x4*)&Ks[kdst] = kv;
        *(u32x4*)&VsT[vdst] = vv;
        __syncthreads();                    // staging visible

        // ---- S^T = K . Q^T ----
        bf16x8 a00 = *(const bf16x8*)&Ks[ka00];
        bf16x8 a01 = *(const bf16x8*)&Ks[ka01];
        bf16x8 a10 = *(const bf16x8*)&Ks[ka10];
        bf16x8 a11 = *(const bf16x8*)&Ks[ka11];
        f32x4 st0 = zero, st1 = zero;
        st0 = __builtin_amdgcn_mfma_f32_16x16x32_bf16(a00, bQ0, st0, 0, 0, 0);
        st0 = __builtin_amdgcn_mfma_f32_16x16x32_bf16(a01, bQ1, st0, 0, 0, 0);
        st1 = __builtin_amdgcn_mfma_f32_16x16x32_bf16(a10, bQ0, st1, 0, 0, 0);
        st1 = __builtin_amdgcn_mfma_f32_16x16x32_bf16(a11, bQ1, st1, 0, 0, 0);

        // ---- online softmax (lane: q = c16, 8 key values) ----
        float sv[8];
        float mloc = -1e30f;
        #pragma unroll
        for (int f = 0; f < 2; ++f)
            #pragma unroll
            for (int r = 0; r < 4; ++r) {
                int kg = kt * 32 + 16 * f + 4 * g + r;
                float s = ((f == 0) ? st0[r] : st1[r]) * 0.125f;
                s = (kg < Ns) ? s : -1e30f;
                sv[f * 4 + r] = s;
                mloc = fmaxf(mloc, s);
            }
        mloc = fmaxf(mloc, __shfl_xor(mloc, 16));
        mloc = fmaxf(mloc, __shfl_xor(mloc, 32));
        if (!__all(mloc - mrun <= 8.f)) {          // defer-max (THR=8)
            float mnew = fmaxf(mrun, mloc);
            float sc = exp2f((mrun - mnew) * L2E);
            lrun *= sc;
            #pragma unroll
            for (int j = 0; j < 4; ++j) {
                Oacc[j][0] *= sc; Oacc[j][1] *= sc;
                Oacc[j][2] *= sc; Oacc[j][3] *= sc;
            }
            mrun = mnew;
        }
        float nl = mrun * L2E;
        float p[8];
        float psum = 0.f;
        #pragma unroll
        for (int e = 0; e < 8; ++e) {
            p[e] = exp2f(fmaf(sv[e], L2E, -nl));
            psum += p[e];
        }
        psum += __shfl_xor(psum, 16);
        psum += __shfl_xor(psum, 32);
        lrun += psum;

        // ---- pack P (sequential pairs -> sigma key order) ----
        union { unsigned int u[4]; bf16x8 v; } pku;
        #pragma unroll
        for (int wi = 0; wi < 4; ++wi)
            asm("v_cvt_pk_bf16_f32 %0, %1, %2"
                : "=v"(pku.u[wi]) : "v"(p[2 * wi]), "v"(p[2 * wi + 1]));
        bf16x8 bP = pku.v;

        // ---- O^T += V^T . P^T  (A-frag via sigma: keys 4g..4g+3, 16+4g..) ----
        #pragma unroll
        for (int j = 0; j < 4; ++j) {
            int vb = (16 * j + c16) * 36 + 4 * g;
            bf16x4_t lo = *(const bf16x4_t*)&VsT[vb];
            bf16x4_t hi = *(const bf16x4_t*)&VsT[vb + 16];
            bf16x8 aV;
            aV[0] = lo[0]; aV[1] = lo[1]; aV[2] = lo[2]; aV[3] = lo[3];
            aV[4] = hi[0]; aV[5] = hi[1]; aV[6] = hi[2]; aV[7] = hi[3];
            Oacc[j] = __builtin_amdgcn_mfma_f32_16x16x32_bf16(aV, bP, Oacc[j], 0, 0, 0);
        }
    }

    if (qrow < Ns) {
        float inv = 1.f / lrun;
        unsigned short* op = o + (size_t)(mb + qrow) * 512 + h * 64;
        #pragma unroll
        for (int j = 0; j < 4; ++j)
            #pragma unroll
            for (int r = 0; r < 4; ++r)
                op[16 * j + 4 * g + r] = f2bf(Oacc[j][r] * inv);
    }
}

// ---------------------------------------------------------------------------
extern "C" void kernel_launch(void* const* d_in, const int* in_sizes, int n_in,
                              void* d_out, int out_size, void* d_ws, size_t ws_size,
                              hipStream_t stream)
{
    const float* x       = (const float*)d_in[0];
    const float* ln1_g   = (const float*)d_in[2];
    const float* ln1_b   = (const float*)d_in[3];
    const float* ln2_g   = (const float*)d_in[4];
    const float* ln2_b   = (const float*)d_in[5];
    const float* ln3_g   = (const float*)d_in[6];
    const float* ln3_b   = (const float*)d_in[7];
    const float* g_qkv_w = (const float*)d_in[8];
    const float* g_qkv_b = (const float*)d_in[9];
    const float* g_proj_w= (const float*)d_in[10];
    const float* g_proj_b= (const float*)d_in[11];
    const float* l_qkv_w = (const float*)d_in[12];
    const float* l_qkv_b = (const float*)d_in[13];
    const float* l_proj_w= (const float*)d_in[14];
    const float* l_proj_b= (const float*)d_in[15];
    const float* mlp_w1  = (const float*)d_in[16];
    const float* mlp_b1  = (const float*)d_in[17];
    const float* mlp_w2  = (const float*)d_in[18];
    const float* mlp_b2  = (const float*)d_in[19];

    float* out = (float*)d_out;

    // ws layout (ushort units)
    unsigned short* buf_a = (unsigned short*)d_ws;            // [6274][512] ln/attn bf16
    unsigned short* buf_b = buf_a + (size_t)6274 * 512;       // [6274][2048] qk / hidden
    unsigned short* vTb   = buf_b + (size_t)6274 * 2048;      // vT: max(2*512*3144, 32*512*200)
    unsigned short* wbf   = vTb + (size_t)3276800 + 64;
    unsigned short* g_qkv_t  = wbf;                           // [1536][512]
    unsigned short* g_proj_t = g_qkv_t + 1536 * 512;          // [512][512]
    unsigned short* l_qkv_t  = g_proj_t + 512 * 512;          // [1536][512]
    unsigned short* l_proj_t = l_qkv_t + 1536 * 512;          // [512][512]
    unsigned short* w1_t     = l_proj_t + 512 * 512;          // [2048][512]
    unsigned short* w2_t     = w1_t + (size_t)2048 * 512;     // [512][2048]

    unsigned int M3137 = (unsigned int)((0x100000000ULL + 3136) / 3137);
    unsigned int M196  = (unsigned int)((0x100000000ULL + 195) / 196);

    dim3 tb(32, 8);
    transpose_bf16_kernel<<<dim3(48, 16), tb, 0, stream>>>(g_qkv_w, g_qkv_t, 512, 1536);
    transpose_bf16_kernel<<<dim3(16, 16), tb, 0, stream>>>(g_proj_w, g_proj_t, 512, 512);
    transpose_bf16_kernel<<<dim3(48, 16), tb, 0, stream>>>(l_qkv_w, l_qkv_t, 512, 1536);
    transpose_bf16_kernel<<<dim3(16, 16), tb, 0, stream>>>(l_proj_w, l_proj_t, 512, 512);
    transpose_bf16_kernel<<<dim3(64, 16), tb, 0, stream>>>(mlp_w1, w1_t, 512, 2048);
    transpose_bf16_kernel<<<dim3(16, 64), tb, 0, stream>>>(mlp_w2, w2_t, 2048, 512);

    // 1) ln1 = LN(x) -> bf16
    ln_kernel<<<6274, 64, 0, stream>>>(x, ln1_g, ln1_b, buf_a, 0);
    // 2a) qk_g = ln1 @ Wqk -> [6274][1024]
    mfma_gemm<1><<<dim3(50, 8), 256, 0, stream>>>(
        buf_a, g_qkv_t, g_qkv_b, nullptr, buf_b, 6274, 1024, 512, 0, 0, 0, 0, 0u, 0);
    // 2b) vT_g = Wv^T @ ln1^T -> [2][512][3144]
    mfma_gemm<1><<<dim3(4, 50), 256, 0, stream>>>(
        g_qkv_t + 1024 * 512, buf_a, g_qkv_b + 1024, nullptr, vTb,
        512, 6274, 512, 0, 0, 1, 3137, M3137, 3144);
    // 3) global attention
    attn_mfma<<<dim3(50, 8, 2), 256, 0, stream>>>(buf_b, vTb, buf_a, 3137, 3144);
    // 4) x1 = x + attn @ g_proj
    mfma_gemm<0><<<dim3(50, 4), 256, 0, stream>>>(
        buf_a, g_proj_t, g_proj_b, x, out, 6274, 512, 512, 0, 0, 0, 0, 0u, 0);
    // 5) ln2 over patch rows -> bf16
    ln_kernel<<<6272, 64, 0, stream>>>(out, ln2_g, ln2_b, buf_a, 1);
    // 6a) qk_l
    mfma_gemm<1><<<dim3(49, 8), 256, 0, stream>>>(
        buf_a, l_qkv_t, l_qkv_b, nullptr, buf_b, 6272, 1024, 512, 0, 0, 0, 0, 0u, 0);
    // 6b) vT_l -> [32][512][200]
    mfma_gemm<1><<<dim3(4, 49), 256, 0, stream>>>(
        l_qkv_t + 1024 * 512, buf_a, l_qkv_b + 1024, nullptr, vTb,
        512, 6272, 512, 0, 0, 1, 196, M196, 200);
    // 7) local attention (32 sub-batches of 196)
    attn_mfma<<<dim3(4, 8, 32), 256, 0, stream>>>(buf_b, vTb, buf_a, 196, 200);
    // 8) patches += local @ l_proj  (rowmap)
    mfma_gemm<0><<<dim3(49, 4), 256, 0, stream>>>(
        buf_a, l_proj_t, l_proj_b, out, out, 6272, 512, 512, 1, 0, 0, 0, 0u, 0);
    // 9) ln3 -> bf16
    ln_kernel<<<6274, 64, 0, stream>>>(out, ln3_g, ln3_b, buf_a, 0);
    // 10) hidden = gelu(ln3 @ w1 + b1) -> bf16
    mfma_gemm<1><<<dim3(50, 16), 256, 0, stream>>>(
        buf_a, w1_t, mlp_b1, nullptr, buf_b, 6274, 2048, 512, 0, 1, 0, 0, 0u, 0);
    // 11) out = x2 + hidden @ w2 + b2
    mfma_gemm<0><<<dim3(50, 4), 256, 0, stream>>>(
        buf_b, w2_t, mlp_b2, out, out, 6274, 512, 2048, 0, 0, 0, 0, 0u, 0);
}

// Round 5
// 527.156 us; speedup vs baseline: 1.1804x; 1.1804x over previous
//
#include <hip/hip_runtime.h>
#include <math.h>

typedef __attribute__((ext_vector_type(8))) short bf16x8;
typedef __attribute__((ext_vector_type(4))) short bf16x4_t;
typedef __attribute__((ext_vector_type(4))) float f32x4;
typedef __attribute__((ext_vector_type(4))) unsigned int u32x4;

typedef const __attribute__((address_space(1))) unsigned int glb_u32;
typedef __attribute__((address_space(3))) unsigned int lds_u32;
#define GLOAD_LDS16(g, l) __builtin_amdgcn_global_load_lds( \
    (glb_u32*)(const void*)(g), (lds_u32*)(void*)(l), 16, 0, 0)

static __device__ __forceinline__ float4 ld4(const float* p) {
    return *reinterpret_cast<const float4*>(p);
}
static __device__ __forceinline__ unsigned short f2bf(float f) {
    unsigned int u = __float_as_uint(f);
    u += 0x7fffu + ((u >> 16) & 1u);
    return (unsigned short)(u >> 16);
}

// ---------------------------------------------------------------------------
// LayerNorm: one wave per row of 512, bf16 output.
// mode=1: in_row = r + 1 + r/3136 (patch rows of (2,3137,512)).
// ---------------------------------------------------------------------------
__global__ __launch_bounds__(64) void ln_kernel(
    const float* __restrict__ in, const float* __restrict__ g,
    const float* __restrict__ bta, unsigned short* __restrict__ out, int mode)
{
    int r = blockIdx.x;
    int lane = threadIdx.x;
    int in_r = mode ? (r + 1 + r / 3136) : r;
    const float* xp = in + (size_t)in_r * 512 + lane * 8;
    float4 v0 = ld4(xp), v1 = ld4(xp + 4);
    float s  = v0.x + v0.y + v0.z + v0.w + v1.x + v1.y + v1.z + v1.w;
    float sq = v0.x*v0.x + v0.y*v0.y + v0.z*v0.z + v0.w*v0.w
             + v1.x*v1.x + v1.y*v1.y + v1.z*v1.z + v1.w*v1.w;
    #pragma unroll
    for (int off = 32; off; off >>= 1) {
        s  += __shfl_xor(s, off);
        sq += __shfl_xor(sq, off);
    }
    float mean = s * (1.f / 512.f);
    float var  = fmaxf(sq * (1.f / 512.f) - mean * mean, 0.f);
    float rstd = rsqrtf(var + 1e-5f);
    float4 g0 = ld4(g + lane * 8),   g1 = ld4(g + lane * 8 + 4);
    float4 b0 = ld4(bta + lane * 8), b1 = ld4(bta + lane * 8 + 4);
    float o0 = (v0.x - mean) * rstd * g0.x + b0.x;
    float o1 = (v0.y - mean) * rstd * g0.y + b0.y;
    float o2 = (v0.z - mean) * rstd * g0.z + b0.z;
    float o3 = (v0.w - mean) * rstd * g0.w + b0.w;
    float o4 = (v1.x - mean) * rstd * g1.x + b1.x;
    float o5 = (v1.y - mean) * rstd * g1.y + b1.y;
    float o6 = (v1.z - mean) * rstd * g1.z + b1.z;
    float o7 = (v1.w - mean) * rstd * g1.w + b1.w;
    u32x4 pk;
    pk[0] = (unsigned int)f2bf(o0) | ((unsigned int)f2bf(o1) << 16);
    pk[1] = (unsigned int)f2bf(o2) | ((unsigned int)f2bf(o3) << 16);
    pk[2] = (unsigned int)f2bf(o4) | ((unsigned int)f2bf(o5) << 16);
    pk[3] = (unsigned int)f2bf(o6) | ((unsigned int)f2bf(o7) << 16);
    *(u32x4*)(out + (size_t)r * 512 + lane * 8) = pk;
}

// ---------------------------------------------------------------------------
// Weight transpose + fp32->bf16: W[K][N] -> WT[N][K] bf16.
// ---------------------------------------------------------------------------
__global__ __launch_bounds__(256) void transpose_bf16_kernel(
    const float* __restrict__ W, unsigned short* __restrict__ WT, int K, int N)
{
    __shared__ unsigned short tile[32][34];
    int tx = threadIdx.x, ty = threadIdx.y;
    int bx = blockIdx.x * 32, by = blockIdx.y * 32;
    #pragma unroll
    for (int r = 0; r < 32; r += 8)
        tile[ty + r][tx] = f2bf(W[(size_t)(by + ty + r) * N + bx + tx]);
    __syncthreads();
    #pragma unroll
    for (int r = 0; r < 32; r += 8)
        WT[(size_t)(bx + ty + r) * K + by + tx] = tile[tx][ty + r];
}

// ---------------------------------------------------------------------------
// MFMA bf16 GEMM, m97-style: global_load_lds(16B) -> linear LDS -> MFMA.
// out[maprow(m)] (+)= A[m,:] @ WT[n,:] + bias (+gelu)(+resid)
// A: MxK bf16, WT: rows x K bf16. BM x 128 tile, BK=32, 4 waves (2x2).
// Wave tile (BM/2) x 64; frags FI x 4 of 16x16x32. OOB rows read in-ws
// garbage and are masked at the epilogue.
// vtNs!=0: output layout [batch][512][vtNsP], batch = col / vtNs (magic mul).
// ---------------------------------------------------------------------------
template<int BM, int OUT_BF16>
__global__ __launch_bounds__(256) void mfma_gemm(
    const unsigned short* __restrict__ A, const unsigned short* __restrict__ WT,
    const float* __restrict__ bias, const float* __restrict__ resid,
    void* __restrict__ outp, int M, int N, int K,
    int rowmap, int act, int biasrow,
    int vtNs, unsigned int vtMagic, int vtNsP)
{
    constexpr int FI = BM / 32;          // m-frags per wave (2 or 4)
    constexpr int AI = BM / 64;          // A gload issues per wave (1 or 2)
    __shared__ __align__(16) unsigned short As[BM * 32];
    __shared__ __align__(16) unsigned short Bs[128 * 32];

    int tid = threadIdx.x;
    int m0 = blockIdx.x * BM, n0 = blockIdx.y * 128;
    int w = tid >> 6, l = tid & 63;
    int wm = (w >> 1) * (BM / 2), wn = (w & 1) * 64;
    int lr = l & 15, lg = l >> 4;

    int lrow = l >> 2;            // 0..15: row within 16-row staging chunk
    int lcol = (l & 3) * 8;       // 0,8,16,24: elem offset (16B chunk)

    f32x4 zero = {0.f, 0.f, 0.f, 0.f};
    f32x4 acc[FI][4];
    #pragma unroll
    for (int i = 0; i < FI; ++i)
        #pragma unroll
        for (int j = 0; j < 4; ++j) acc[i][j] = zero;

    for (int k0 = 0; k0 < K; k0 += 32) {
        __syncthreads();          // previous tile fully consumed
        #pragma unroll
        for (int q = 0; q < AI; ++q) {
            int rowbase = (w * AI + q) * 16;
            const unsigned short* gp =
                A + (size_t)(m0 + rowbase + lrow) * K + k0 + lcol;
            GLOAD_LDS16(gp, As + rowbase * 32);
        }
        #pragma unroll
        for (int q = 0; q < 2; ++q) {
            int rowbase = (w * 2 + q) * 16;
            const unsigned short* gp =
                WT + (size_t)(n0 + rowbase + lrow) * K + k0 + lcol;
            GLOAD_LDS16(gp, Bs + rowbase * 32);
        }
        __syncthreads();          // vmcnt(0) drain + barrier: staging visible

        bf16x8 af[FI], bfr[4];
        #pragma unroll
        for (int i = 0; i < FI; ++i)
            af[i] = *(const bf16x8*)&As[(wm + i * 16 + lr) * 32 + lg * 8];
        #pragma unroll
        for (int j = 0; j < 4; ++j)
            bfr[j] = *(const bf16x8*)&Bs[(wn + j * 16 + lr) * 32 + lg * 8];
        #pragma unroll
        for (int i = 0; i < FI; ++i)
            #pragma unroll
            for (int j = 0; j < 4; ++j)
                acc[i][j] = __builtin_amdgcn_mfma_f32_16x16x32_bf16(
                    af[i], bfr[j], acc[i][j], 0, 0, 0);
    }

    // D layout: col = lane&15, row = (lane>>4)*4 + reg.
    #pragma unroll
    for (int i = 0; i < FI; ++i) {
        #pragma unroll
        for (int r = 0; r < 4; ++r) {
            int row = m0 + wm + i * 16 + lg * 4 + r;
            if (row >= M) continue;
            int orow = rowmap ? (row + 1 + row / 3136) : row;
            #pragma unroll
            for (int j = 0; j < 4; ++j) {
                int col = n0 + wn + j * 16 + lr;
                if (col >= N) continue;
                float v = acc[i][j][r] + (biasrow ? bias[row] : bias[col]);
                if (act) v = 0.5f * v * (1.f + erff(v * 0.70710678118654752f));
                if (resid) v += resid[(size_t)orow * N + col];
                if (vtNs) {
                    unsigned int bb = (unsigned int)(((unsigned long long)(unsigned int)col * vtMagic) >> 32);
                    int nn = col - (int)bb * vtNs;
                    ((unsigned short*)outp)[((size_t)bb * 512 + row) * vtNsP + nn] = f2bf(v);
                } else if (OUT_BF16) {
                    ((unsigned short*)outp)[(size_t)orow * N + col] = f2bf(v);
                } else {
                    ((float*)outp)[(size_t)orow * N + col] = v;
                }
            }
        }
    }
}

// ---------------------------------------------------------------------------
// MFMA flash attention, bf16, no P round-trip, V^T pre-transposed in global.
// qk: [Mtot][1024] rows = [q(512)|k(512)]; vT: [batch][512][NsP].
// Block = 4 waves x 16 q-rows. S^T = mfma(K, Q): lane -> q=lane&15,
// key_local = 16f + 4g + reg. P packed per-lane (key slot sigma:
// key(g,i) = 16*(i>>2) + 4g + (i&3)); V A-frag gathered with same sigma
// = two conflict-free ds_read_b64 from VsT[64][36] (stride-36 pad).
// ---------------------------------------------------------------------------
__global__ __launch_bounds__(256) void attn_mfma(
    const unsigned short* __restrict__ qk, const unsigned short* __restrict__ vT,
    unsigned short* __restrict__ o, int Ns, int NsP)
{
    __shared__ __align__(16) unsigned short Ks[32 * 64];
    __shared__ __align__(16) unsigned short VsT[64 * 36];

    int tid = threadIdx.x;
    int h = blockIdx.y, b = blockIdx.z;
    int mb = b * Ns;
    int l = tid & 63, w = tid >> 6;
    int g = l >> 4, c16 = l & 15;

    int qrow = blockIdx.x * 64 + w * 16 + c16;
    int qr = (qrow < Ns ? qrow : Ns - 1) + mb;
    const unsigned short* qp = qk + (size_t)qr * 1024 + h * 64;
    bf16x8 bQ0 = *(const bf16x8*)(qp + g * 8);
    bf16x8 bQ1 = *(const bf16x8*)(qp + 32 + g * 8);

    f32x4 zero = {0.f, 0.f, 0.f, 0.f};
    f32x4 Oacc[4] = {zero, zero, zero, zero};
    float mrun = -1e30f, lrun = 0.f;

    // K staging: thread -> key row sk, 16B chunk sch, xor-swizzled dest.
    int sk = tid >> 3, sch = tid & 7;
    int kdst = sk * 64 + ((sch ^ (sk & 7) ^ (sk >> 3)) * 8);
    // V staging: thread -> dim sd, key chunk skc (8 keys).
    int sd = tid >> 2, skc = tid & 3;
    const unsigned short* vrow = vT + ((size_t)b * 512 + h * 64 + sd) * NsP;
    int vdst = sd * 36 + skc * 8;

    // Hoisted K-frag LDS offsets.
    int swz0 = (c16 & 7) ^ (c16 >> 3);
    int swz1 = (c16 & 7) ^ ((16 + c16) >> 3);
    int ka00 = c16 * 64 + ((g ^ swz0) * 8);
    int ka01 = c16 * 64 + (((4 + g) ^ swz0) * 8);
    int ka10 = (16 + c16) * 64 + ((g ^ swz1) * 8);
    int ka11 = (16 + c16) * 64 + (((4 + g) ^ swz1) * 8);

    const float L2E = 1.4426950408889634f;
    int nt = (Ns + 31) >> 5;
    for (int kt = 0; kt < nt; ++kt) {
        int kr = kt * 32 + sk; if (kr >= Ns) kr = Ns - 1;
        u32x4 kv = *(const u32x4*)(qk + (size_t)(mb + kr) * 1024 + 512 + h * 64 + sch * 8);
        u32x4 vv = *(const u32x4*)(vrow + kt * 32 + skc * 8);
        __syncthreads();                    // prev tile fully consumed
        *(u32x4*)&Ks[kdst] = kv;
        *(u32x4*)&VsT[vdst] = vv;
        __syncthreads();                    // staging visible

        // ---- S^T = K . Q^T ----
        bf16x8 a00 = *(const bf16x8*)&Ks[ka00];
        bf16x8 a01 = *(const bf16x8*)&Ks[ka01];
        bf16x8 a10 = *(const bf16x8*)&Ks[ka10];
        bf16x8 a11 = *(const bf16x8*)&Ks[ka11];
        f32x4 st0 = zero, st1 = zero;
        st0 = __builtin_amdgcn_mfma_f32_16x16x32_bf16(a00, bQ0, st0, 0, 0, 0);
        st0 = __builtin_amdgcn_mfma_f32_16x16x32_bf16(a01, bQ1, st0, 0, 0, 0);
        st1 = __builtin_amdgcn_mfma_f32_16x16x32_bf16(a10, bQ0, st1, 0, 0, 0);
        st1 = __builtin_amdgcn_mfma_f32_16x16x32_bf16(a11, bQ1, st1, 0, 0, 0);

        // ---- online softmax (lane: q = c16, 8 key values) ----
        float sv[8];
        float mloc = -1e30f;
        #pragma unroll
        for (int f = 0; f < 2; ++f)
            #pragma unroll
            for (int r = 0; r < 4; ++r) {
                int kg = kt * 32 + 16 * f + 4 * g + r;
                float s = ((f == 0) ? st0[r] : st1[r]) * 0.125f;
                s = (kg < Ns) ? s : -1e30f;
                sv[f * 4 + r] = s;
                mloc = fmaxf(mloc, s);
            }
        mloc = fmaxf(mloc, __shfl_xor(mloc, 16));
        mloc = fmaxf(mloc, __shfl_xor(mloc, 32));
        if (!__all(mloc - mrun <= 8.f)) {          // defer-max (THR=8)
            float mnew = fmaxf(mrun, mloc);
            float sc = exp2f((mrun - mnew) * L2E);
            lrun *= sc;
            #pragma unroll
            for (int j = 0; j < 4; ++j) {
                Oacc[j][0] *= sc; Oacc[j][1] *= sc;
                Oacc[j][2] *= sc; Oacc[j][3] *= sc;
            }
            mrun = mnew;
        }
        float nl = mrun * L2E;
        float p[8];
        float psum = 0.f;
        #pragma unroll
        for (int e = 0; e < 8; ++e) {
            p[e] = exp2f(fmaf(sv[e], L2E, -nl));
            psum += p[e];
        }
        psum += __shfl_xor(psum, 16);
        psum += __shfl_xor(psum, 32);
        lrun += psum;

        // ---- pack P (sequential pairs -> sigma key order) ----
        union { unsigned int u[4]; bf16x8 v; } pku;
        #pragma unroll
        for (int wi = 0; wi < 4; ++wi)
            asm("v_cvt_pk_bf16_f32 %0, %1, %2"
                : "=v"(pku.u[wi]) : "v"(p[2 * wi]), "v"(p[2 * wi + 1]));
        bf16x8 bP = pku.v;

        // ---- O^T += V^T . P^T  (A-frag via sigma: keys 4g..4g+3, 16+4g..) ----
        #pragma unroll
        for (int j = 0; j < 4; ++j) {
            int vb = (16 * j + c16) * 36 + 4 * g;
            bf16x4_t lo = *(const bf16x4_t*)&VsT[vb];
            bf16x4_t hi = *(const bf16x4_t*)&VsT[vb + 16];
            bf16x8 aV;
            aV[0] = lo[0]; aV[1] = lo[1]; aV[2] = lo[2]; aV[3] = lo[3];
            aV[4] = hi[0]; aV[5] = hi[1]; aV[6] = hi[2]; aV[7] = hi[3];
            Oacc[j] = __builtin_amdgcn_mfma_f32_16x16x32_bf16(aV, bP, Oacc[j], 0, 0, 0);
        }
    }

    if (qrow < Ns) {
        float inv = 1.f / lrun;
        unsigned short* op = o + (size_t)(mb + qrow) * 512 + h * 64;
        #pragma unroll
        for (int j = 0; j < 4; ++j)
            #pragma unroll
            for (int r = 0; r < 4; ++r)
                op[16 * j + 4 * g + r] = f2bf(Oacc[j][r] * inv);
    }
}

// ---------------------------------------------------------------------------
extern "C" void kernel_launch(void* const* d_in, const int* in_sizes, int n_in,
                              void* d_out, int out_size, void* d_ws, size_t ws_size,
                              hipStream_t stream)
{
    const float* x       = (const float*)d_in[0];
    const float* ln1_g   = (const float*)d_in[2];
    const float* ln1_b   = (const float*)d_in[3];
    const float* ln2_g   = (const float*)d_in[4];
    const float* ln2_b   = (const float*)d_in[5];
    const float* ln3_g   = (const float*)d_in[6];
    const float* ln3_b   = (const float*)d_in[7];
    const float* g_qkv_w = (const float*)d_in[8];
    const float* g_qkv_b = (const float*)d_in[9];
    const float* g_proj_w= (const float*)d_in[10];
    const float* g_proj_b= (const float*)d_in[11];
    const float* l_qkv_w = (const float*)d_in[12];
    const float* l_qkv_b = (const float*)d_in[13];
    const float* l_proj_w= (const float*)d_in[14];
    const float* l_proj_b= (const float*)d_in[15];
    const float* mlp_w1  = (const float*)d_in[16];
    const float* mlp_b1  = (const float*)d_in[17];
    const float* mlp_w2  = (const float*)d_in[18];
    const float* mlp_b2  = (const float*)d_in[19];

    float* out = (float*)d_out;

    // ws layout (ushort units)
    unsigned short* buf_a = (unsigned short*)d_ws;            // [6274][512] ln/attn bf16
    unsigned short* buf_b = buf_a + (size_t)6274 * 512;       // [6274][2048] qk / hidden
    unsigned short* vTb   = buf_b + (size_t)6274 * 2048;      // vT: max(2*512*3144, 32*512*200)
    unsigned short* wbf   = vTb + (size_t)3276800 + 64;
    unsigned short* g_qkv_t  = wbf;                           // [1536][512]
    unsigned short* g_proj_t = g_qkv_t + 1536 * 512;          // [512][512]
    unsigned short* l_qkv_t  = g_proj_t + 512 * 512;          // [1536][512]
    unsigned short* l_proj_t = l_qkv_t + 1536 * 512;          // [512][512]
    unsigned short* w1_t     = l_proj_t + 512 * 512;          // [2048][512]
    unsigned short* w2_t     = w1_t + (size_t)2048 * 512;     // [512][2048]

    unsigned int M3137 = (unsigned int)((0x100000000ULL + 3136) / 3137);
    unsigned int M196  = (unsigned int)((0x100000000ULL + 195) / 196);

    dim3 tb(32, 8);
    transpose_bf16_kernel<<<dim3(48, 16), tb, 0, stream>>>(g_qkv_w, g_qkv_t, 512, 1536);
    transpose_bf16_kernel<<<dim3(16, 16), tb, 0, stream>>>(g_proj_w, g_proj_t, 512, 512);
    transpose_bf16_kernel<<<dim3(48, 16), tb, 0, stream>>>(l_qkv_w, l_qkv_t, 512, 1536);
    transpose_bf16_kernel<<<dim3(16, 16), tb, 0, stream>>>(l_proj_w, l_proj_t, 512, 512);
    transpose_bf16_kernel<<<dim3(64, 16), tb, 0, stream>>>(mlp_w1, w1_t, 512, 2048);
    transpose_bf16_kernel<<<dim3(16, 64), tb, 0, stream>>>(mlp_w2, w2_t, 2048, 512);

    // 1) ln1 = LN(x) -> bf16
    ln_kernel<<<6274, 64, 0, stream>>>(x, ln1_g, ln1_b, buf_a, 0);
    // 2a) qk_g = ln1 @ Wqk -> [6274][1024]
    mfma_gemm<128,1><<<dim3(50, 8), 256, 0, stream>>>(
        buf_a, g_qkv_t, g_qkv_b, nullptr, buf_b, 6274, 1024, 512, 0, 0, 0, 0, 0u, 0);
    // 2b) vT_g = Wv^T @ ln1^T -> [2][512][3144]
    mfma_gemm<64,1><<<dim3(8, 50), 256, 0, stream>>>(
        g_qkv_t + 1024 * 512, buf_a, g_qkv_b + 1024, nullptr, vTb,
        512, 6274, 512, 0, 0, 1, 3137, M3137, 3144);
    // 3) global attention
    attn_mfma<<<dim3(50, 8, 2), 256, 0, stream>>>(buf_b, vTb, buf_a, 3137, 3144);
    // 4) x1 = x + attn @ g_proj
    mfma_gemm<64,0><<<dim3(99, 4), 256, 0, stream>>>(
        buf_a, g_proj_t, g_proj_b, x, out, 6274, 512, 512, 0, 0, 0, 0, 0u, 0);
    // 5) ln2 over patch rows -> bf16
    ln_kernel<<<6272, 64, 0, stream>>>(out, ln2_g, ln2_b, buf_a, 1);
    // 6a) qk_l
    mfma_gemm<128,1><<<dim3(49, 8), 256, 0, stream>>>(
        buf_a, l_qkv_t, l_qkv_b, nullptr, buf_b, 6272, 1024, 512, 0, 0, 0, 0, 0u, 0);
    // 6b) vT_l -> [32][512][200]
    mfma_gemm<64,1><<<dim3(8, 49), 256, 0, stream>>>(
        l_qkv_t + 1024 * 512, buf_a, l_qkv_b + 1024, nullptr, vTb,
        512, 6272, 512, 0, 0, 1, 196, M196, 200);
    // 7) local attention (32 sub-batches of 196)
    attn_mfma<<<dim3(4, 8, 32), 256, 0, stream>>>(buf_b, vTb, buf_a, 196, 200);
    // 8) patches += local @ l_proj  (rowmap)
    mfma_gemm<64,0><<<dim3(98, 4), 256, 0, stream>>>(
        buf_a, l_proj_t, l_proj_b, out, out, 6272, 512, 512, 1, 0, 0, 0, 0u, 0);
    // 9) ln3 -> bf16
    ln_kernel<<<6274, 64, 0, stream>>>(out, ln3_g, ln3_b, buf_a, 0);
    // 10) hidden = gelu(ln3 @ w1 + b1) -> bf16
    mfma_gemm<128,1><<<dim3(50, 16), 256, 0, stream>>>(
        buf_a, w1_t, mlp_b1, nullptr, buf_b, 6274, 2048, 512, 0, 1, 0, 0, 0u, 0);
    // 11) out = x2 + hidden @ w2 + b2
    mfma_gemm<64,0><<<dim3(99, 4), 256, 0, stream>>>(
        buf_b, w2_t, mlp_b2, out, out, 6274, 512, 2048, 0, 0, 0, 0, 0u, 0);
}

// Round 6
// 415.543 us; speedup vs baseline: 1.4975x; 1.2686x over previous
//
#include <hip/hip_runtime.h>
#include <math.h>

typedef __attribute__((ext_vector_type(8))) short bf16x8;
typedef __attribute__((ext_vector_type(4))) short bf16x4_t;
typedef __attribute__((ext_vector_type(4))) float f32x4;
typedef __attribute__((ext_vector_type(4))) unsigned int u32x4;

typedef const __attribute__((address_space(1))) unsigned int glb_u32;
typedef __attribute__((address_space(3))) unsigned int lds_u32;
#define GLOAD_LDS16(g, l) __builtin_amdgcn_global_load_lds( \
    (glb_u32*)(const void*)(g), (lds_u32*)(void*)(l), 16, 0, 0)

static __device__ __forceinline__ float4 ld4(const float* p) {
    return *reinterpret_cast<const float4*>(p);
}
static __device__ __forceinline__ unsigned short f2bf(float f) {
    unsigned int u = __float_as_uint(f);
    u += 0x7fffu + ((u >> 16) & 1u);
    return (unsigned short)(u >> 16);
}

// ---------------------------------------------------------------------------
// LayerNorm: one wave per row of 512, bf16 output.
// mode=1: in_row = r + 1 + r/3136 (patch rows of (2,3137,512)).
// ---------------------------------------------------------------------------
__global__ __launch_bounds__(64) void ln_kernel(
    const float* __restrict__ in, const float* __restrict__ g,
    const float* __restrict__ bta, unsigned short* __restrict__ out, int mode)
{
    int r = blockIdx.x;
    int lane = threadIdx.x;
    int in_r = mode ? (r + 1 + r / 3136) : r;
    const float* xp = in + (size_t)in_r * 512 + lane * 8;
    float4 v0 = ld4(xp), v1 = ld4(xp + 4);
    float s  = v0.x + v0.y + v0.z + v0.w + v1.x + v1.y + v1.z + v1.w;
    float sq = v0.x*v0.x + v0.y*v0.y + v0.z*v0.z + v0.w*v0.w
             + v1.x*v1.x + v1.y*v1.y + v1.z*v1.z + v1.w*v1.w;
    #pragma unroll
    for (int off = 32; off; off >>= 1) {
        s  += __shfl_xor(s, off);
        sq += __shfl_xor(sq, off);
    }
    float mean = s * (1.f / 512.f);
    float var  = fmaxf(sq * (1.f / 512.f) - mean * mean, 0.f);
    float rstd = rsqrtf(var + 1e-5f);
    float4 g0 = ld4(g + lane * 8),   g1 = ld4(g + lane * 8 + 4);
    float4 b0 = ld4(bta + lane * 8), b1 = ld4(bta + lane * 8 + 4);
    float o0 = (v0.x - mean) * rstd * g0.x + b0.x;
    float o1 = (v0.y - mean) * rstd * g0.y + b0.y;
    float o2 = (v0.z - mean) * rstd * g0.z + b0.z;
    float o3 = (v0.w - mean) * rstd * g0.w + b0.w;
    float o4 = (v1.x - mean) * rstd * g1.x + b1.x;
    float o5 = (v1.y - mean) * rstd * g1.y + b1.y;
    float o6 = (v1.z - mean) * rstd * g1.z + b1.z;
    float o7 = (v1.w - mean) * rstd * g1.w + b1.w;
    u32x4 pk;
    pk[0] = (unsigned int)f2bf(o0) | ((unsigned int)f2bf(o1) << 16);
    pk[1] = (unsigned int)f2bf(o2) | ((unsigned int)f2bf(o3) << 16);
    pk[2] = (unsigned int)f2bf(o4) | ((unsigned int)f2bf(o5) << 16);
    pk[3] = (unsigned int)f2bf(o6) | ((unsigned int)f2bf(o7) << 16);
    *(u32x4*)(out + (size_t)r * 512 + lane * 8) = pk;
}

// ---------------------------------------------------------------------------
// Weight transpose + fp32->bf16: W[K][N] -> WT[N][K] bf16.
// ---------------------------------------------------------------------------
__global__ __launch_bounds__(256) void transpose_bf16_kernel(
    const float* __restrict__ W, unsigned short* __restrict__ WT, int K, int N)
{
    __shared__ unsigned short tile[32][34];
    int tx = threadIdx.x, ty = threadIdx.y;
    int bx = blockIdx.x * 32, by = blockIdx.y * 32;
    #pragma unroll
    for (int r = 0; r < 32; r += 8)
        tile[ty + r][tx] = f2bf(W[(size_t)(by + ty + r) * N + bx + tx]);
    __syncthreads();
    #pragma unroll
    for (int r = 0; r < 32; r += 8)
        WT[(size_t)(bx + ty + r) * K + by + tx] = tile[tx][ty + r];
}

// ---------------------------------------------------------------------------
// MFMA bf16 GEMM, double-buffered global_load_lds, 1 barrier per K-step.
// out[maprow(m)] (+)= A[m,:] @ WT[n,:] + bias[col] (+gelu)(+resid)
// vt_out: cols >= vtColBase go to transposed-v layout
//   [b = row/vtNs][c = col-vtColBase][token = row%vtNs], token stride vtNsP.
// Row-major part has width vtColBase when vt_out set, else N.
// ---------------------------------------------------------------------------
template<int BM, int OUT_BF16>
__global__ __launch_bounds__(256) void mfma_gemm(
    const unsigned short* __restrict__ A, const unsigned short* __restrict__ WT,
    const float* __restrict__ bias, const float* __restrict__ resid,
    void* __restrict__ outp, int M, int N, int K,
    int rowmap, int act,
    unsigned short* __restrict__ vt_out,
    int vtNs, unsigned int vtMagic, int vtNsP, int vtColBase)
{
    constexpr int FI = BM / 32;          // m-frags per wave
    constexpr int AI = BM / 64;          // A gload issues per wave
    __shared__ __align__(16) unsigned short As[2][BM * 32];
    __shared__ __align__(16) unsigned short Bs[2][128 * 32];

    int tid = threadIdx.x;
    int m0 = blockIdx.x * BM, n0 = blockIdx.y * 128;
    int w = tid >> 6, l = tid & 63;
    int wm = (w >> 1) * (BM / 2), wn = (w & 1) * 64;
    int lr = l & 15, lg = l >> 4;

    int lrow = l >> 2;            // row within 16-row staging chunk
    int lcol = (l & 3) * 8;       // 16B chunk offset

    f32x4 zero = {0.f, 0.f, 0.f, 0.f};
    f32x4 acc[FI][4];
    #pragma unroll
    for (int i = 0; i < FI; ++i)
        #pragma unroll
        for (int j = 0; j < 4; ++j) acc[i][j] = zero;

#define STAGE(buf, kk) do { \
    _Pragma("unroll") \
    for (int q = 0; q < AI; ++q) { \
        int rb = (w * AI + q) * 16; \
        GLOAD_LDS16(A + (size_t)(m0 + rb + lrow) * K + (kk) + lcol, \
                    &As[buf][rb * 32]); \
    } \
    _Pragma("unroll") \
    for (int q = 0; q < 2; ++q) { \
        int rb = (w * 2 + q) * 16; \
        GLOAD_LDS16(WT + (size_t)(n0 + rb + lrow) * K + (kk) + lcol, \
                    &Bs[buf][rb * 32]); \
    } \
} while (0)

    int nk = K >> 5;
    STAGE(0, 0);
    for (int s = 0; s < nk; ++s) {
        int cur = s & 1;
        __syncthreads();                 // drains vmcnt: buf[cur] ready; prev compute done
        if (s + 1 < nk) STAGE(cur ^ 1, (s + 1) * 32);

        bf16x8 af[FI], bfr[4];
        #pragma unroll
        for (int i = 0; i < FI; ++i)
            af[i] = *(const bf16x8*)&As[cur][(wm + i * 16 + lr) * 32 + lg * 8];
        #pragma unroll
        for (int j = 0; j < 4; ++j)
            bfr[j] = *(const bf16x8*)&Bs[cur][(wn + j * 16 + lr) * 32 + lg * 8];
        #pragma unroll
        for (int i = 0; i < FI; ++i)
            #pragma unroll
            for (int j = 0; j < 4; ++j)
                acc[i][j] = __builtin_amdgcn_mfma_f32_16x16x32_bf16(
                    af[i], bfr[j], acc[i][j], 0, 0, 0);
    }
#undef STAGE

    int rowW = vt_out ? vtColBase : N;
    // D layout: col = lane&15, row = (lane>>4)*4 + reg.
    #pragma unroll
    for (int i = 0; i < FI; ++i) {
        #pragma unroll
        for (int r = 0; r < 4; ++r) {
            int row = m0 + wm + i * 16 + lg * 4 + r;
            if (row >= M) continue;
            int orow = rowmap ? (row + 1 + row / 3136) : row;
            #pragma unroll
            for (int j = 0; j < 4; ++j) {
                int col = n0 + wn + j * 16 + lr;
                if (col >= N) continue;
                float v = acc[i][j][r] + bias[col];
                if (act) v = 0.5f * v * (1.f + erff(v * 0.70710678118654752f));
                if (resid) v += resid[(size_t)orow * N + col];
                if (vt_out && col >= vtColBase) {
                    unsigned int bb = (unsigned int)(((unsigned long long)(unsigned int)row * vtMagic) >> 32);
                    int nn = row - (int)bb * vtNs;
                    vt_out[((size_t)bb * 512 + (col - vtColBase)) * vtNsP + nn] = f2bf(v);
                } else if (OUT_BF16) {
                    ((unsigned short*)outp)[(size_t)orow * rowW + col] = f2bf(v);
                } else {
                    ((float*)outp)[(size_t)orow * rowW + col] = v;
                }
            }
        }
    }
}

// ---------------------------------------------------------------------------
// MFMA flash attention, bf16. KVBLK=64, register-prefetch of next tile.
// qk: [Mtot][1024] = [q(512)|k(512)]; vT: [batch][512][NsP].
// Block = 4 waves x 16 q-rows. S^T = mfma(K, Q): lane -> q=lane&15,
// key_local = 16f + 4g + reg. P packed per-lane; slot sigma
// key(g,i) = 16*(i>>2) + 4g + (i&3) shared by P B-frag and V A-frag.
// Ks[64][64] xor-chunk-swizzled; VsT[64 dims][72] (stride pad).
// Scale 0.125 folded into exp2 constant; masking only in tail tile.
// ---------------------------------------------------------------------------
__global__ __launch_bounds__(256) void attn_mfma(
    const unsigned short* __restrict__ qk, const unsigned short* __restrict__ vT,
    unsigned short* __restrict__ o, int Ns, int NsP)
{
    __shared__ __align__(16) unsigned short Ks[64 * 64];
    __shared__ __align__(16) unsigned short VsT[64 * 72];

    int tid = threadIdx.x;
    int h = blockIdx.y, b = blockIdx.z;
    int mb = b * Ns;
    int l = tid & 63, w = tid >> 6;
    int g = l >> 4, c16 = l & 15;

    int qrow = blockIdx.x * 64 + w * 16 + c16;
    int qr = (qrow < Ns ? qrow : Ns - 1) + mb;
    const unsigned short* qp = qk + (size_t)qr * 1024 + h * 64;
    bf16x8 bQ0 = *(const bf16x8*)(qp + g * 8);
    bf16x8 bQ1 = *(const bf16x8*)(qp + 32 + g * 8);

    f32x4 zero = {0.f, 0.f, 0.f, 0.f};
    f32x4 Oacc[4] = {zero, zero, zero, zero};
    float mrun = -1e30f, lrun = 0.f;

    // staging: thread -> row sk (K: key; V: dim), chunks sc0 and sc0+4.
    int sk = tid >> 2, sc0 = tid & 3;
    int kswz = (sk & 7) ^ (sk >> 3);
    int kdst0 = sk * 64 + ((sc0 ^ kswz) * 8);
    int kdst1 = sk * 64 + (((sc0 + 4) ^ kswz) * 8);
    int vdst0 = sk * 72 + sc0 * 8;
    int vdst1 = sk * 72 + (sc0 + 4) * 8;
    const unsigned short* kbase = qk + (size_t)mb * 1024 + 512 + h * 64;
    const unsigned short* vrow = vT + ((size_t)b * 512 + h * 64 + sk) * NsP;

    // K-frag LDS offsets (keys 16f + c16)
    int ka[4][2];
    #pragma unroll
    for (int f = 0; f < 4; ++f) {
        int key = 16 * f + c16;
        int swz = (key & 7) ^ (key >> 3);
        ka[f][0] = key * 64 + ((g ^ swz) * 8);
        ka[f][1] = key * 64 + (((4 + g) ^ swz) * 8);
    }

    const float SCL = 0.125f * 1.4426950408889634f;  // scale * log2(e)
    int nt = (Ns + 63) >> 6;
    int tail = Ns & 63;

    u32x4 kv0, kv1, vv0, vv1;
    {
        int kr = sk < Ns ? sk : Ns - 1;
        const unsigned short* kp = kbase + (size_t)kr * 1024;
        kv0 = *(const u32x4*)(kp + sc0 * 8);
        kv1 = *(const u32x4*)(kp + (sc0 + 4) * 8);
        vv0 = *(const u32x4*)(vrow + sc0 * 8);
        vv1 = *(const u32x4*)(vrow + (sc0 + 4) * 8);
    }

    for (int kt = 0; kt < nt; ++kt) {
        __syncthreads();                    // prev tile fully consumed
        *(u32x4*)&Ks[kdst0] = kv0;
        *(u32x4*)&Ks[kdst1] = kv1;
        *(u32x4*)&VsT[vdst0] = vv0;
        *(u32x4*)&VsT[vdst1] = vv1;
        __syncthreads();                    // staging visible

        if (kt + 1 < nt) {                  // prefetch next tile into regs
            int kr = (kt + 1) * 64 + sk; if (kr >= Ns) kr = Ns - 1;
            const unsigned short* kp = kbase + (size_t)kr * 1024;
            kv0 = *(const u32x4*)(kp + sc0 * 8);
            kv1 = *(const u32x4*)(kp + (sc0 + 4) * 8);
            int kb = (kt + 1) * 64;
            vv0 = *(const u32x4*)(vrow + kb + sc0 * 8);
            vv1 = *(const u32x4*)(vrow + kb + (sc0 + 4) * 8);
        }

        // ---- S^T = K . Q^T  (4 key-frags x 2 k-chunks) ----
        f32x4 st[4];
        #pragma unroll
        for (int f = 0; f < 4; ++f) {
            bf16x8 a0 = *(const bf16x8*)&Ks[ka[f][0]];
            bf16x8 a1 = *(const bf16x8*)&Ks[ka[f][1]];
            f32x4 a = zero;
            a = __builtin_amdgcn_mfma_f32_16x16x32_bf16(a0, bQ0, a, 0, 0, 0);
            a = __builtin_amdgcn_mfma_f32_16x16x32_bf16(a1, bQ1, a, 0, 0, 0);
            st[f] = a;
        }

        // ---- online softmax (lane: q = c16, 16 key values, raw units) ----
        float sv[16];
        #pragma unroll
        for (int f = 0; f < 4; ++f)
            #pragma unroll
            for (int r = 0; r < 4; ++r) sv[4 * f + r] = st[f][r];
        if (kt == nt - 1 && tail) {
            #pragma unroll
            for (int f = 0; f < 4; ++f)
                #pragma unroll
                for (int r = 0; r < 4; ++r)
                    if (16 * f + 4 * g + r >= tail) sv[4 * f + r] = -1e30f;
        }
        float mloc = sv[0];
        #pragma unroll
        for (int e = 1; e < 16; ++e) mloc = fmaxf(mloc, sv[e]);
        mloc = fmaxf(mloc, __shfl_xor(mloc, 16));
        mloc = fmaxf(mloc, __shfl_xor(mloc, 32));
        if (!__all(mloc - mrun <= 64.f)) {   // defer-max (8 in scaled units)
            float mnew = fmaxf(mrun, mloc);
            float sc = exp2f((mrun - mnew) * SCL);
            lrun *= sc;
            #pragma unroll
            for (int j = 0; j < 4; ++j) {
                Oacc[j][0] *= sc; Oacc[j][1] *= sc;
                Oacc[j][2] *= sc; Oacc[j][3] *= sc;
            }
            mrun = mnew;
        }
        float nl = mrun * SCL;
        float psum = 0.f;
        #pragma unroll
        for (int e = 0; e < 16; ++e) {
            sv[e] = exp2f(fmaf(sv[e], SCL, -nl));
            psum += sv[e];
        }
        psum += __shfl_xor(psum, 16);
        psum += __shfl_xor(psum, 32);
        lrun += psum;

        // ---- pack P: two B-frags (keys 0..31, 32..63 in sigma order) ----
        union { unsigned int u[4]; bf16x8 v; } plo, phi;
        #pragma unroll
        for (int wi = 0; wi < 4; ++wi) {
            asm("v_cvt_pk_bf16_f32 %0, %1, %2"
                : "=v"(plo.u[wi]) : "v"(sv[2 * wi]), "v"(sv[2 * wi + 1]));
            asm("v_cvt_pk_bf16_f32 %0, %1, %2"
                : "=v"(phi.u[wi]) : "v"(sv[8 + 2 * wi]), "v"(sv[8 + 2 * wi + 1]));
        }

        // ---- O^T += V^T . P^T (A-frags via sigma; 2 MFMA per d-group) ----
        #pragma unroll
        for (int j = 0; j < 4; ++j) {
            int vb = (16 * j + c16) * 72 + 4 * g;
            bf16x4_t t0 = *(const bf16x4_t*)&VsT[vb];
            bf16x4_t t1 = *(const bf16x4_t*)&VsT[vb + 16];
            bf16x4_t t2 = *(const bf16x4_t*)&VsT[vb + 32];
            bf16x4_t t3 = *(const bf16x4_t*)&VsT[vb + 48];
            bf16x8 aVlo, aVhi;
            aVlo[0]=t0[0]; aVlo[1]=t0[1]; aVlo[2]=t0[2]; aVlo[3]=t0[3];
            aVlo[4]=t1[0]; aVlo[5]=t1[1]; aVlo[6]=t1[2]; aVlo[7]=t1[3];
            aVhi[0]=t2[0]; aVhi[1]=t2[1]; aVhi[2]=t2[2]; aVhi[3]=t2[3];
            aVhi[4]=t3[0]; aVhi[5]=t3[1]; aVhi[6]=t3[2]; aVhi[7]=t3[3];
            Oacc[j] = __builtin_amdgcn_mfma_f32_16x16x32_bf16(aVlo, plo.v, Oacc[j], 0, 0, 0);
            Oacc[j] = __builtin_amdgcn_mfma_f32_16x16x32_bf16(aVhi, phi.v, Oacc[j], 0, 0, 0);
        }
    }

    if (qrow < Ns) {
        float inv = 1.f / lrun;
        unsigned short* op = o + (size_t)(mb + qrow) * 512 + h * 64;
        #pragma unroll
        for (int j = 0; j < 4; ++j)
            #pragma unroll
            for (int r = 0; r < 4; ++r)
                op[16 * j + 4 * g + r] = f2bf(Oacc[j][r] * inv);
    }
}

// ---------------------------------------------------------------------------
extern "C" void kernel_launch(void* const* d_in, const int* in_sizes, int n_in,
                              void* d_out, int out_size, void* d_ws, size_t ws_size,
                              hipStream_t stream)
{
    const float* x       = (const float*)d_in[0];
    const float* ln1_g   = (const float*)d_in[2];
    const float* ln1_b   = (const float*)d_in[3];
    const float* ln2_g   = (const float*)d_in[4];
    const float* ln2_b   = (const float*)d_in[5];
    const float* ln3_g   = (const float*)d_in[6];
    const float* ln3_b   = (const float*)d_in[7];
    const float* g_qkv_w = (const float*)d_in[8];
    const float* g_qkv_b = (const float*)d_in[9];
    const float* g_proj_w= (const float*)d_in[10];
    const float* g_proj_b= (const float*)d_in[11];
    const float* l_qkv_w = (const float*)d_in[12];
    const float* l_qkv_b = (const float*)d_in[13];
    const float* l_proj_w= (const float*)d_in[14];
    const float* l_proj_b= (const float*)d_in[15];
    const float* mlp_w1  = (const float*)d_in[16];
    const float* mlp_b1  = (const float*)d_in[17];
    const float* mlp_w2  = (const float*)d_in[18];
    const float* mlp_b2  = (const float*)d_in[19];

    float* out = (float*)d_out;

    // ws layout (ushort units)
    unsigned short* buf_a = (unsigned short*)d_ws;            // [6274][512] ln/attn bf16
    unsigned short* buf_b = buf_a + (size_t)6274 * 512;       // [6274][2048] qk / hidden
    unsigned short* vTb   = buf_b + (size_t)6274 * 2048;      // vT
    unsigned short* wbf   = vTb + (size_t)3276800 + 64;
    unsigned short* g_qkv_t  = wbf;                           // [1536][512]
    unsigned short* g_proj_t = g_qkv_t + 1536 * 512;          // [512][512]
    unsigned short* l_qkv_t  = g_proj_t + 512 * 512;          // [1536][512]
    unsigned short* l_proj_t = l_qkv_t + 1536 * 512;          // [512][512]
    unsigned short* w1_t     = l_proj_t + 512 * 512;          // [2048][512]
    unsigned short* w2_t     = w1_t + (size_t)2048 * 512;     // [512][2048]

    unsigned int M3137 = (unsigned int)((0x100000000ULL + 3136) / 3137);
    unsigned int M196  = (unsigned int)((0x100000000ULL + 195) / 196);

    dim3 tb(32, 8);
    transpose_bf16_kernel<<<dim3(48, 16), tb, 0, stream>>>(g_qkv_w, g_qkv_t, 512, 1536);
    transpose_bf16_kernel<<<dim3(16, 16), tb, 0, stream>>>(g_proj_w, g_proj_t, 512, 512);
    transpose_bf16_kernel<<<dim3(48, 16), tb, 0, stream>>>(l_qkv_w, l_qkv_t, 512, 1536);
    transpose_bf16_kernel<<<dim3(16, 16), tb, 0, stream>>>(l_proj_w, l_proj_t, 512, 512);
    transpose_bf16_kernel<<<dim3(64, 16), tb, 0, stream>>>(mlp_w1, w1_t, 512, 2048);
    transpose_bf16_kernel<<<dim3(16, 64), tb, 0, stream>>>(mlp_w2, w2_t, 2048, 512);

    // 1) ln1 = LN(x) -> bf16
    ln_kernel<<<6274, 64, 0, stream>>>(x, ln1_g, ln1_b, buf_a, 0);
    // 2) merged qkv_g: cols<1024 -> qk row-major [6274][1024], cols>=1024 -> vT
    mfma_gemm<128,1><<<dim3(50, 12), 256, 0, stream>>>(
        buf_a, g_qkv_t, g_qkv_b, nullptr, buf_b, 6274, 1536, 512, 0, 0,
        vTb, 3137, M3137, 3144, 1024);
    // 3) global attention
    attn_mfma<<<dim3(50, 8, 2), 256, 0, stream>>>(buf_b, vTb, buf_a, 3137, 3144);
    // 4) x1 = x + attn @ g_proj
    mfma_gemm<64,0><<<dim3(99, 4), 256, 0, stream>>>(
        buf_a, g_proj_t, g_proj_b, x, out, 6274, 512, 512, 0, 0,
        nullptr, 0, 0u, 0, 0);
    // 5) ln2 over patch rows -> bf16
    ln_kernel<<<6272, 64, 0, stream>>>(out, ln2_g, ln2_b, buf_a, 1);
    // 6) merged qkv_l
    mfma_gemm<128,1><<<dim3(49, 12), 256, 0, stream>>>(
        buf_a, l_qkv_t, l_qkv_b, nullptr, buf_b, 6272, 1536, 512, 0, 0,
        vTb, 196, M196, 200, 1024);
    // 7) local attention (32 sub-batches of 196)
    attn_mfma<<<dim3(4, 8, 32), 256, 0, stream>>>(buf_b, vTb, buf_a, 196, 200);
    // 8) patches += local @ l_proj  (rowmap)
    mfma_gemm<64,0><<<dim3(98, 4), 256, 0, stream>>>(
        buf_a, l_proj_t, l_proj_b, out, out, 6272, 512, 512, 1, 0,
        nullptr, 0, 0u, 0, 0);
    // 9) ln3 -> bf16
    ln_kernel<<<6274, 64, 0, stream>>>(out, ln3_g, ln3_b, buf_a, 0);
    // 10) hidden = gelu(ln3 @ w1 + b1) -> bf16
    mfma_gemm<128,1><<<dim3(50, 16), 256, 0, stream>>>(
        buf_a, w1_t, mlp_b1, nullptr, buf_b, 6274, 2048, 512, 0, 1,
        nullptr, 0, 0u, 0, 0);
    // 11) out = x2 + hidden @ w2 + b2
    mfma_gemm<64,0><<<dim3(99, 4), 256, 0, stream>>>(
        buf_b, w2_t, mlp_b2, out, out, 6274, 512, 2048, 0, 0,
        nullptr, 0, 0u, 0, 0);
}

// Round 7
// 377.277 us; speedup vs baseline: 1.6494x; 1.1014x over previous
//
#include <hip/hip_runtime.h>
#include <math.h>

typedef __attribute__((ext_vector_type(8))) short bf16x8;
typedef __attribute__((ext_vector_type(4))) short bf16x4_t;
typedef __attribute__((ext_vector_type(4))) float f32x4;
typedef __attribute__((ext_vector_type(4))) unsigned int u32x4;

typedef const __attribute__((address_space(1))) unsigned int glb_u32;
typedef __attribute__((address_space(3))) unsigned int lds_u32;
#define GLOAD_LDS16(g, l) __builtin_amdgcn_global_load_lds( \
    (glb_u32*)(const void*)(g), (lds_u32*)(void*)(l), 16, 0, 0)

static __device__ __forceinline__ float4 ld4(const float* p) {
    return *reinterpret_cast<const float4*>(p);
}
static __device__ __forceinline__ unsigned short f2bf(float f) {
    unsigned int u = __float_as_uint(f);
    u += 0x7fffu + ((u >> 16) & 1u);
    return (unsigned short)(u >> 16);
}

// ---------------------------------------------------------------------------
// LayerNorm: one wave per row of 512, bf16 output.
// mode=1: in_row = r + 1 + r/3136 (patch rows of (2,3137,512)).
// ---------------------------------------------------------------------------
__global__ __launch_bounds__(64) void ln_kernel(
    const float* __restrict__ in, const float* __restrict__ g,
    const float* __restrict__ bta, unsigned short* __restrict__ out, int mode)
{
    int r = blockIdx.x;
    int lane = threadIdx.x;
    int in_r = mode ? (r + 1 + r / 3136) : r;
    const float* xp = in + (size_t)in_r * 512 + lane * 8;
    float4 v0 = ld4(xp), v1 = ld4(xp + 4);
    float s  = v0.x + v0.y + v0.z + v0.w + v1.x + v1.y + v1.z + v1.w;
    float sq = v0.x*v0.x + v0.y*v0.y + v0.z*v0.z + v0.w*v0.w
             + v1.x*v1.x + v1.y*v1.y + v1.z*v1.z + v1.w*v1.w;
    #pragma unroll
    for (int off = 32; off; off >>= 1) {
        s  += __shfl_xor(s, off);
        sq += __shfl_xor(sq, off);
    }
    float mean = s * (1.f / 512.f);
    float var  = fmaxf(sq * (1.f / 512.f) - mean * mean, 0.f);
    float rstd = rsqrtf(var + 1e-5f);
    float4 g0 = ld4(g + lane * 8),   g1 = ld4(g + lane * 8 + 4);
    float4 b0 = ld4(bta + lane * 8), b1 = ld4(bta + lane * 8 + 4);
    float o0 = (v0.x - mean) * rstd * g0.x + b0.x;
    float o1 = (v0.y - mean) * rstd * g0.y + b0.y;
    float o2 = (v0.z - mean) * rstd * g0.z + b0.z;
    float o3 = (v0.w - mean) * rstd * g0.w + b0.w;
    float o4 = (v1.x - mean) * rstd * g1.x + b1.x;
    float o5 = (v1.y - mean) * rstd * g1.y + b1.y;
    float o6 = (v1.z - mean) * rstd * g1.z + b1.z;
    float o7 = (v1.w - mean) * rstd * g1.w + b1.w;
    u32x4 pk;
    pk[0] = (unsigned int)f2bf(o0) | ((unsigned int)f2bf(o1) << 16);
    pk[1] = (unsigned int)f2bf(o2) | ((unsigned int)f2bf(o3) << 16);
    pk[2] = (unsigned int)f2bf(o4) | ((unsigned int)f2bf(o5) << 16);
    pk[3] = (unsigned int)f2bf(o6) | ((unsigned int)f2bf(o7) << 16);
    *(u32x4*)(out + (size_t)r * 512 + lane * 8) = pk;
}

// ---------------------------------------------------------------------------
// All six weight transposes in one launch. W[K][N] -> WT[N][K] bf16.
// ---------------------------------------------------------------------------
struct TransArgs {
    const float* src[6];
    unsigned short* dst[6];
    int N[6], K[6], off[6];
};

__global__ __launch_bounds__(256) void transpose_all(TransArgs a)
{
    __shared__ unsigned short tile[32][34];
    int t = blockIdx.x;
    int i = 0;
    #pragma unroll
    for (int j = 1; j < 6; ++j) if (t >= a.off[j]) i = j;
    int rel = t - a.off[i];
    int tx_n = a.N[i] >> 5;
    int bx = (rel % tx_n) * 32, by = (rel / tx_n) * 32;
    const float* W = a.src[i];
    unsigned short* WT = a.dst[i];
    int K = a.K[i], N = a.N[i];
    int tx = threadIdx.x & 31, ty = threadIdx.x >> 5;
    #pragma unroll
    for (int r = 0; r < 32; r += 8)
        tile[ty + r][tx] = f2bf(W[(size_t)(by + ty + r) * N + bx + tx]);
    __syncthreads();
    #pragma unroll
    for (int r = 0; r < 32; r += 8)
        WT[(size_t)(bx + ty + r) * K + by + tx] = tile[tx][ty + r];
}

// ---------------------------------------------------------------------------
// MFMA bf16 GEMM, depth-2 pipelined global_load_lds (counted vmcnt, raw
// barriers). out[maprow(m)] (+)= A[m,:] @ WT[n,:] + bias[col] (+gelu)(+resid)
// 4 waves as 2x2 over BM x BN; BK=32. vt_out: cols >= vtColBase go to
// [b][col-vtColBase][token] layout (token stride vtNsP, b = row/vtNs).
// ---------------------------------------------------------------------------
template<int BM, int BN, int OUT_BF16>
__global__ __launch_bounds__(256) void mfma_gemm(
    const unsigned short* __restrict__ A, const unsigned short* __restrict__ WT,
    const float* __restrict__ bias, const float* __restrict__ resid,
    void* __restrict__ outp, int M, int N, int K,
    int rowmap, int act,
    unsigned short* __restrict__ vt_out,
    int vtNs, unsigned int vtMagic, int vtNsP, int vtColBase)
{
    constexpr int FI = BM / 32, FJ = BN / 32;
    constexpr int AL = BM / 64, BL = BN / 64;
    __shared__ __align__(16) unsigned short As[2][BM * 32];
    __shared__ __align__(16) unsigned short Bs[2][BN * 32];

    int tid = threadIdx.x;
    int m0 = blockIdx.x * BM, n0 = blockIdx.y * BN;
    int w = tid >> 6, l = tid & 63;
    int wm = (w >> 1) * (BM / 2), wn = (w & 1) * (BN / 2);
    int lr = l & 15, lg = l >> 4;

    int lrow = l >> 2;            // row within 16-row staging chunk
    int lcol = (l & 3) * 8;       // 16B chunk offset

    f32x4 zero = {0.f, 0.f, 0.f, 0.f};
    f32x4 acc[FI][FJ];
    #pragma unroll
    for (int i = 0; i < FI; ++i)
        #pragma unroll
        for (int j = 0; j < FJ; ++j) acc[i][j] = zero;

#define STAGE(buf, kk) do { \
    _Pragma("unroll") \
    for (int q = 0; q < AL; ++q) { \
        int rb = (w * AL + q) * 16; \
        GLOAD_LDS16(A + (size_t)(m0 + rb + lrow) * K + (kk) + lcol, \
                    &As[buf][rb * 32]); \
    } \
    _Pragma("unroll") \
    for (int q = 0; q < BL; ++q) { \
        int rb = (w * BL + q) * 16; \
        GLOAD_LDS16(WT + (size_t)(n0 + rb + lrow) * K + (kk) + lcol, \
                    &Bs[buf][rb * 32]); \
    } \
} while (0)

    int nk = K >> 5;
    STAGE(0, 0);
    STAGE(1, 32);
    for (int s = 0; s < nk; ++s) {
        int cur = s & 1;
        if (s + 1 < nk) {
            if constexpr (AL + BL == 2)
                asm volatile("s_waitcnt vmcnt(2)" ::: "memory");
            else if constexpr (AL + BL == 3)
                asm volatile("s_waitcnt vmcnt(3)" ::: "memory");
            else
                asm volatile("s_waitcnt vmcnt(4)" ::: "memory");
        } else {
            asm volatile("s_waitcnt vmcnt(0)" ::: "memory");
        }
        __builtin_amdgcn_s_barrier();     // buf[cur] staged for all waves

        bf16x8 af[FI], bfr[FJ];
        #pragma unroll
        for (int i = 0; i < FI; ++i)
            af[i] = *(const bf16x8*)&As[cur][(wm + i * 16 + lr) * 32 + lg * 8];
        #pragma unroll
        for (int j = 0; j < FJ; ++j)
            bfr[j] = *(const bf16x8*)&Bs[cur][(wn + j * 16 + lr) * 32 + lg * 8];
        asm volatile("s_waitcnt lgkmcnt(0)" ::: "memory");
        __builtin_amdgcn_sched_barrier(0);
        __builtin_amdgcn_s_barrier();     // all waves done reading buf[cur]
        if (s + 2 < nk) STAGE(cur, (s + 2) * 32);

        #pragma unroll
        for (int i = 0; i < FI; ++i)
            #pragma unroll
            for (int j = 0; j < FJ; ++j)
                acc[i][j] = __builtin_amdgcn_mfma_f32_16x16x32_bf16(
                    af[i], bfr[j], acc[i][j], 0, 0, 0);
    }
#undef STAGE

    int rowW = vt_out ? vtColBase : N;
    // D layout: col = lane&15, row = (lane>>4)*4 + reg.
    #pragma unroll
    for (int i = 0; i < FI; ++i) {
        #pragma unroll
        for (int r = 0; r < 4; ++r) {
            int row = m0 + wm + i * 16 + lg * 4 + r;
            if (row >= M) continue;
            int orow = rowmap ? (row + 1 + row / 3136) : row;
            #pragma unroll
            for (int j = 0; j < FJ; ++j) {
                int col = n0 + wn + j * 16 + lr;
                if (col >= N) continue;
                float v = acc[i][j][r] + bias[col];
                if (act) v = 0.5f * v * (1.f + erff(v * 0.70710678118654752f));
                if (resid) v += resid[(size_t)orow * N + col];
                if (vt_out && col >= vtColBase) {
                    unsigned int bb = (unsigned int)(((unsigned long long)(unsigned int)row * vtMagic) >> 32);
                    int nn = row - (int)bb * vtNs;
                    vt_out[((size_t)bb * 512 + (col - vtColBase)) * vtNsP + nn] = f2bf(v);
                } else if (OUT_BF16) {
                    ((unsigned short*)outp)[(size_t)orow * rowW + col] = f2bf(v);
                } else {
                    ((float*)outp)[(size_t)orow * rowW + col] = v;
                }
            }
        }
    }
}

// ---------------------------------------------------------------------------
// MFMA flash attention, bf16. KVBLK=64, register-prefetch of next tile.
// qk: [Mtot][1024] = [q(512)|k(512)]; vT: [batch][512][NsP].
// Block = 4 waves x 16 q-rows. S^T = mfma(K, Q): lane -> q=lane&15,
// key_local = 16f + 4g + reg. P packed per-lane; slot sigma
// key(g,i) = 16*(i>>2) + 4g + (i&3) shared by P B-frag and V A-frag.
// Cross-lane reduces deferred: lrun kept per-lane; max-reduce only on the
// (rare) defer-max trigger. aV built by shufflevector (register concat).
// ---------------------------------------------------------------------------
__global__ __launch_bounds__(256) void attn_mfma(
    const unsigned short* __restrict__ qk, const unsigned short* __restrict__ vT,
    unsigned short* __restrict__ o, int Ns, int NsP)
{
    __shared__ __align__(16) unsigned short Ks[64 * 64];
    __shared__ __align__(16) unsigned short VsT[64 * 72];

    int tid = threadIdx.x;
    int h = blockIdx.y, b = blockIdx.z;
    int mb = b * Ns;
    int l = tid & 63, w = tid >> 6;
    int g = l >> 4, c16 = l & 15;

    int qrow = blockIdx.x * 64 + w * 16 + c16;
    int qr = (qrow < Ns ? qrow : Ns - 1) + mb;
    const unsigned short* qp = qk + (size_t)qr * 1024 + h * 64;
    bf16x8 bQ0 = *(const bf16x8*)(qp + g * 8);
    bf16x8 bQ1 = *(const bf16x8*)(qp + 32 + g * 8);

    f32x4 zero = {0.f, 0.f, 0.f, 0.f};
    f32x4 Oacc[4] = {zero, zero, zero, zero};
    float mrun = -1e30f, lrun = 0.f;      // lrun is a per-lane partial sum

    // staging: thread -> row sk (K: key; V: dim), chunks sc0 and sc0+4.
    int sk = tid >> 2, sc0 = tid & 3;
    int kswz = (sk & 7) ^ (sk >> 3);
    int kdst0 = sk * 64 + ((sc0 ^ kswz) * 8);
    int kdst1 = sk * 64 + (((sc0 + 4) ^ kswz) * 8);
    int vdst0 = sk * 72 + sc0 * 8;
    int vdst1 = sk * 72 + (sc0 + 4) * 8;
    const unsigned short* kbase = qk + (size_t)mb * 1024 + 512 + h * 64;
    const unsigned short* vrow = vT + ((size_t)b * 512 + h * 64 + sk) * NsP;

    // K-frag LDS offsets (keys 16f + c16)
    int ka[4][2];
    #pragma unroll
    for (int f = 0; f < 4; ++f) {
        int key = 16 * f + c16;
        int swz = (key & 7) ^ (key >> 3);
        ka[f][0] = key * 64 + ((g ^ swz) * 8);
        ka[f][1] = key * 64 + (((4 + g) ^ swz) * 8);
    }

    const float SCL = 0.125f * 1.4426950408889634f;  // scale * log2(e)
    int nt = (Ns + 63) >> 6;
    int tail = Ns & 63;

    u32x4 kv0, kv1, vv0, vv1;
    {
        int kr = sk < Ns ? sk : Ns - 1;
        const unsigned short* kp = kbase + (size_t)kr * 1024;
        kv0 = *(const u32x4*)(kp + sc0 * 8);
        kv1 = *(const u32x4*)(kp + (sc0 + 4) * 8);
        vv0 = *(const u32x4*)(vrow + sc0 * 8);
        vv1 = *(const u32x4*)(vrow + (sc0 + 4) * 8);
    }

    for (int kt = 0; kt < nt; ++kt) {
        __syncthreads();                    // prev tile fully consumed
        *(u32x4*)&Ks[kdst0] = kv0;
        *(u32x4*)&Ks[kdst1] = kv1;
        *(u32x4*)&VsT[vdst0] = vv0;
        *(u32x4*)&VsT[vdst1] = vv1;
        __syncthreads();                    // staging visible

        if (kt + 1 < nt) {                  // prefetch next tile into regs
            int kr = (kt + 1) * 64 + sk; if (kr >= Ns) kr = Ns - 1;
            const unsigned short* kp = kbase + (size_t)kr * 1024;
            kv0 = *(const u32x4*)(kp + sc0 * 8);
            kv1 = *(const u32x4*)(kp + (sc0 + 4) * 8);
            int kb = (kt + 1) * 64;
            vv0 = *(const u32x4*)(vrow + kb + sc0 * 8);
            vv1 = *(const u32x4*)(vrow + kb + (sc0 + 4) * 8);
        }

        // ---- S^T = K . Q^T  (4 key-frags x 2 k-chunks) ----
        f32x4 st[4];
        #pragma unroll
        for (int f = 0; f < 4; ++f) {
            bf16x8 a0 = *(const bf16x8*)&Ks[ka[f][0]];
            bf16x8 a1 = *(const bf16x8*)&Ks[ka[f][1]];
            f32x4 a = zero;
            a = __builtin_amdgcn_mfma_f32_16x16x32_bf16(a0, bQ0, a, 0, 0, 0);
            a = __builtin_amdgcn_mfma_f32_16x16x32_bf16(a1, bQ1, a, 0, 0, 0);
            st[f] = a;
        }

        // ---- online softmax (lane: q = c16, 16 key values, raw units) ----
        float sv[16];
        #pragma unroll
        for (int f = 0; f < 4; ++f)
            #pragma unroll
            for (int r = 0; r < 4; ++r) sv[4 * f + r] = st[f][r];
        if (kt == nt - 1 && tail) {
            #pragma unroll
            for (int f = 0; f < 4; ++f)
                #pragma unroll
                for (int r = 0; r < 4; ++r)
                    if (16 * f + 4 * g + r >= tail) sv[4 * f + r] = -1e30f;
        }
        float mloc = sv[0];
        #pragma unroll
        for (int e = 1; e < 16; ++e) mloc = fmaxf(mloc, sv[e]);
        if (!__all(mloc - mrun <= 64.f)) {   // defer-max trigger (rare)
            mloc = fmaxf(mloc, __shfl_xor(mloc, 16));
            mloc = fmaxf(mloc, __shfl_xor(mloc, 32));
            float mnew = fmaxf(mrun, mloc);
            float sc = exp2f((mrun - mnew) * SCL);
            lrun *= sc;
            #pragma unroll
            for (int j = 0; j < 4; ++j) {
                Oacc[j][0] *= sc; Oacc[j][1] *= sc;
                Oacc[j][2] *= sc; Oacc[j][3] *= sc;
            }
            mrun = mnew;
        }
        float nl = mrun * SCL;
        #pragma unroll
        for (int e = 0; e < 16; ++e) {
            sv[e] = exp2f(fmaf(sv[e], SCL, -nl));
            lrun += sv[e];
        }

        // ---- pack P: two B-frags (keys 0..31, 32..63 in sigma order) ----
        union { unsigned int u[4]; bf16x8 v; } plo, phi;
        #pragma unroll
        for (int wi = 0; wi < 4; ++wi) {
            asm("v_cvt_pk_bf16_f32 %0, %1, %2"
                : "=v"(plo.u[wi]) : "v"(sv[2 * wi]), "v"(sv[2 * wi + 1]));
            asm("v_cvt_pk_bf16_f32 %0, %1, %2"
                : "=v"(phi.u[wi]) : "v"(sv[8 + 2 * wi]), "v"(sv[8 + 2 * wi + 1]));
        }

        // ---- O^T += V^T . P^T (A-frags via sigma; register-concat) ----
        #pragma unroll
        for (int j = 0; j < 4; ++j) {
            int vb = (16 * j + c16) * 72 + 4 * g;
            bf16x4_t t0 = *(const bf16x4_t*)&VsT[vb];
            bf16x4_t t1 = *(const bf16x4_t*)&VsT[vb + 16];
            bf16x4_t t2 = *(const bf16x4_t*)&VsT[vb + 32];
            bf16x4_t t3 = *(const bf16x4_t*)&VsT[vb + 48];
            bf16x8 aVlo = __builtin_shufflevector(t0, t1, 0, 1, 2, 3, 4, 5, 6, 7);
            bf16x8 aVhi = __builtin_shufflevector(t2, t3, 0, 1, 2, 3, 4, 5, 6, 7);
            Oacc[j] = __builtin_amdgcn_mfma_f32_16x16x32_bf16(aVlo, plo.v, Oacc[j], 0, 0, 0);
            Oacc[j] = __builtin_amdgcn_mfma_f32_16x16x32_bf16(aVhi, phi.v, Oacc[j], 0, 0, 0);
        }
    }

    // final cross-lane sum of the per-lane partials (4 lanes per q)
    lrun += __shfl_xor(lrun, 16);
    lrun += __shfl_xor(lrun, 32);

    if (qrow < Ns) {
        float inv = 1.f / lrun;
        unsigned short* op = o + (size_t)(mb + qrow) * 512 + h * 64;
        #pragma unroll
        for (int j = 0; j < 4; ++j) {
            unsigned int u0, u1;
            asm("v_cvt_pk_bf16_f32 %0, %1, %2"
                : "=v"(u0) : "v"(Oacc[j][0] * inv), "v"(Oacc[j][1] * inv));
            asm("v_cvt_pk_bf16_f32 %0, %1, %2"
                : "=v"(u1) : "v"(Oacc[j][2] * inv), "v"(Oacc[j][3] * inv));
            uint2 stv; stv.x = u0; stv.y = u1;
            *(uint2*)(op + 16 * j + 4 * g) = stv;
        }
    }
}

// ---------------------------------------------------------------------------
extern "C" void kernel_launch(void* const* d_in, const int* in_sizes, int n_in,
                              void* d_out, int out_size, void* d_ws, size_t ws_size,
                              hipStream_t stream)
{
    const float* x       = (const float*)d_in[0];
    const float* ln1_g   = (const float*)d_in[2];
    const float* ln1_b   = (const float*)d_in[3];
    const float* ln2_g   = (const float*)d_in[4];
    const float* ln2_b   = (const float*)d_in[5];
    const float* ln3_g   = (const float*)d_in[6];
    const float* ln3_b   = (const float*)d_in[7];
    const float* g_qkv_w = (const float*)d_in[8];
    const float* g_qkv_b = (const float*)d_in[9];
    const float* g_proj_w= (const float*)d_in[10];
    const float* g_proj_b= (const float*)d_in[11];
    const float* l_qkv_w = (const float*)d_in[12];
    const float* l_qkv_b = (const float*)d_in[13];
    const float* l_proj_w= (const float*)d_in[14];
    const float* l_proj_b= (const float*)d_in[15];
    const float* mlp_w1  = (const float*)d_in[16];
    const float* mlp_b1  = (const float*)d_in[17];
    const float* mlp_w2  = (const float*)d_in[18];
    const float* mlp_b2  = (const float*)d_in[19];

    float* out = (float*)d_out;

    // ws layout (ushort units)
    unsigned short* buf_a = (unsigned short*)d_ws;            // [6274][512] ln/attn bf16
    unsigned short* buf_b = buf_a + (size_t)6274 * 512;       // [6274][2048] qk / hidden
    unsigned short* vTb   = buf_b + (size_t)6274 * 2048;      // vT
    unsigned short* wbf   = vTb + (size_t)3276800 + 64;
    unsigned short* g_qkv_t  = wbf;                           // [1536][512]
    unsigned short* g_proj_t = g_qkv_t + 1536 * 512;          // [512][512]
    unsigned short* l_qkv_t  = g_proj_t + 512 * 512;          // [1536][512]
    unsigned short* l_proj_t = l_qkv_t + 1536 * 512;          // [512][512]
    unsigned short* w1_t     = l_proj_t + 512 * 512;          // [2048][512]
    unsigned short* w2_t     = w1_t + (size_t)2048 * 512;     // [512][2048]

    unsigned int M3137 = (unsigned int)((0x100000000ULL + 3136) / 3137);
    unsigned int M196  = (unsigned int)((0x100000000ULL + 195) / 196);

    TransArgs ta;
    ta.src[0] = g_qkv_w;  ta.dst[0] = g_qkv_t;  ta.N[0] = 1536; ta.K[0] = 512;  ta.off[0] = 0;
    ta.src[1] = g_proj_w; ta.dst[1] = g_proj_t; ta.N[1] = 512;  ta.K[1] = 512;  ta.off[1] = 768;
    ta.src[2] = l_qkv_w;  ta.dst[2] = l_qkv_t;  ta.N[2] = 1536; ta.K[2] = 512;  ta.off[2] = 1024;
    ta.src[3] = l_proj_w; ta.dst[3] = l_proj_t; ta.N[3] = 512;  ta.K[3] = 512;  ta.off[3] = 1792;
    ta.src[4] = mlp_w1;   ta.dst[4] = w1_t;     ta.N[4] = 2048; ta.K[4] = 512;  ta.off[4] = 2048;
    ta.src[5] = mlp_w2;   ta.dst[5] = w2_t;     ta.N[5] = 512;  ta.K[5] = 2048; ta.off[5] = 3072;
    transpose_all<<<4096, 256, 0, stream>>>(ta);

    // 1) ln1 = LN(x) -> bf16
    ln_kernel<<<6274, 64, 0, stream>>>(x, ln1_g, ln1_b, buf_a, 0);
    // 2) merged qkv_g: cols<1024 -> qk [6274][1024], cols>=1024 -> vT
    mfma_gemm<128,128,1><<<dim3(50, 12), 256, 0, stream>>>(
        buf_a, g_qkv_t, g_qkv_b, nullptr, buf_b, 6274, 1536, 512, 0, 0,
        vTb, 3137, M3137, 3144, 1024);
    // 3) global attention
    attn_mfma<<<dim3(50, 8, 2), 256, 0, stream>>>(buf_b, vTb, buf_a, 3137, 3144);
    // 4) x1 = x + attn @ g_proj
    mfma_gemm<64,64,0><<<dim3(99, 8), 256, 0, stream>>>(
        buf_a, g_proj_t, g_proj_b, x, out, 6274, 512, 512, 0, 0,
        nullptr, 0, 0u, 0, 0);
    // 5) ln2 over patch rows -> bf16
    ln_kernel<<<6272, 64, 0, stream>>>(out, ln2_g, ln2_b, buf_a, 1);
    // 6) merged qkv_l
    mfma_gemm<128,128,1><<<dim3(49, 12), 256, 0, stream>>>(
        buf_a, l_qkv_t, l_qkv_b, nullptr, buf_b, 6272, 1536, 512, 0, 0,
        vTb, 196, M196, 200, 1024);
    // 7) local attention (32 sub-batches of 196)
    attn_mfma<<<dim3(4, 8, 32), 256, 0, stream>>>(buf_b, vTb, buf_a, 196, 200);
    // 8) patches += local @ l_proj  (rowmap)
    mfma_gemm<64,64,0><<<dim3(98, 8), 256, 0, stream>>>(
        buf_a, l_proj_t, l_proj_b, out, out, 6272, 512, 512, 1, 0,
        nullptr, 0, 0u, 0, 0);
    // 9) ln3 -> bf16
    ln_kernel<<<6274, 64, 0, stream>>>(out, ln3_g, ln3_b, buf_a, 0);
    // 10) hidden = gelu(ln3 @ w1 + b1) -> bf16
    mfma_gemm<128,128,1><<<dim3(50, 16), 256, 0, stream>>>(
        buf_a, w1_t, mlp_b1, nullptr, buf_b, 6274, 2048, 512, 0, 1,
        nullptr, 0, 0u, 0, 0);
    // 11) out = x2 + hidden @ w2 + b2
    mfma_gemm<64,64,0><<<dim3(99, 8), 256, 0, stream>>>(
        buf_b, w2_t, mlp_b2, out, out, 6274, 512, 2048, 0, 0,
        nullptr, 0, 0u, 0, 0);
}